// Round 9
// baseline (106.974 us; speedup 1.0000x reference)
//
#include <hip/hip_runtime.h>
#include <math.h>

// out[b,i,j,f] = min_{di,dj,c} ( x[b,i+di,j+dj,c] - W[di,dj,c,f] )
// x: (16,128,128,16) f32, W: (3,3,16,32) f32, out: (16,126,126,32) f32
//
// R22 = R21 + guaranteed-packed f16 core via non-volatile inline asm.
// Cross-round synthesis (R13..R21): VALU busy-time is INVARIANT at
// ~31-35us across wildly different structures (occupancy 51/48/34%, LDS
// traffic 4x apart, W resident vs remat) -> the kernel is VALU-issue
// bound; dur = ~32us busy + ~15us phase overhead. Hand count of the core
// is only ~73 instr/body = ~16us @2clk -- half the measured busy. Most
// parsimonious explanation: the h2 (2xf16) sub/min ops are being emitted
// UNPACKED (2 scalar v_sub_f16 / cmp+sel per h2 op), doubling the mass:
// ~108 instr/body x 2clk x 23 x 12 waves/SIMD = 31us == measured.
// Fix: pin the opcodes with NON-volatile asm (v_pk_add_f16 neg_lo/hi,
// v_pk_min_f16, v_min_f16). Non-volatile = pure value op: freely
// schedulable, no R19 order-pinning. Zero-cost if codegen was already
// packed (asm == current output) -> clean hypothesis test.
//
// Structure (unchanged from R21):
//  * 512-thread blocks, 8 output cols (grid 16x6x16 = 1536 blocks).
//  * W read once via volatile-asm 9x ds_read_b128 block (remat-proof,
//    R21-verified resident); waves_per_eu(4,4) keeps budget 128.
//  * tile + wbuf read-only after ONE staging barrier; vm separate buffer.
//  * body: rolling 3-row window; full-wave b16 vm writes; ch-halves
//    merged in float4 epilogue (WRITE == out size; R15 lesson: never
//    narrow-store to HBM).

#define TI 21           // output rows per block; 126 = 21*6
#define TROWS (TI + 2)  // input rows per tile (23)
#define NCOL 8          // output cols per block
#define SCOL 10         // staged cols (NCOL + 2 halo)
#define LROW 80         // tile row stride in halves (10 cols * 8 halves)
#define VCOL 68         // vm col stride in halves (64 used + 4 pad)
#define VROW (NCOL * VCOL)  // 544 halves per output row

typedef _Float16 h2 __attribute__((ext_vector_type(2)));

__device__ __forceinline__ h2 hmin2(h2 a, h2 b) {
    return __builtin_elementwise_min(a, b);  // cold paths only
}

// Guaranteed-packed ops (non-volatile: schedulable, CSE-able, opcode pinned)
__device__ __forceinline__ h2 pksub(h2 a, h2 b) {   // a - b, packed
    h2 d;
    asm("v_pk_add_f16 %0, %1, %2 neg_lo:[0,1] neg_hi:[0,1]"
        : "=v"(d) : "v"(a), "v"(b));
    return d;
}
__device__ __forceinline__ h2 pkmin(h2 a, h2 b) {
    h2 d;
    asm("v_pk_min_f16 %0, %1, %2" : "=v"(d) : "v"(a), "v"(b));
    return d;
}
__device__ __forceinline__ _Float16 minh(_Float16 a, _Float16 b) {
    _Float16 d;
    asm("v_min_f16 %0, %1, %2" : "=v"(d) : "v"(a), "v"(b));
    return d;
}

__device__ __forceinline__ h2 pkrtz(float a, float b) {
    auto r = __builtin_amdgcn_cvt_pkrtz(a, b);  // v_cvt_pkrtz_f16_f32
    return *reinterpret_cast<h2*>(&r);
}

// min over 12 half2 of (pr[k] - w[k]) for one weight row di.
__device__ __forceinline__ h2 rowmin3(const float4* pr, const h2* w) {
    h2 t[12];
#pragma unroll
    for (int dj = 0; dj < 3; ++dj) {
        const h2* p = reinterpret_cast<const h2*>(&pr[dj]);
#pragma unroll
        for (int q = 0; q < 4; ++q)
            t[dj * 4 + q] = pksub(p[q], w[dj * 4 + q]);
    }
#pragma unroll
    for (int k = 0; k < 6; ++k) t[k] = pkmin(t[k], t[k + 6]);
    t[0] = pkmin(t[0], t[3]);
    t[1] = pkmin(t[1], t[4]);
    t[2] = pkmin(t[2], t[5]);
    return pkmin(pkmin(t[0], t[1]), t[2]);
}

__global__ __launch_bounds__(512)
__attribute__((amdgpu_waves_per_eu(4, 4)))
void erosion_kernel(
    const float* __restrict__ x, const float* __restrict__ Wt,
    float* __restrict__ out)
{
    __shared__ __align__(16) _Float16 tile[2 * TROWS * LROW];  // 7360 B
    __shared__ __align__(16) _Float16 wbuf[2 * 2304];          // 9216 B
    __shared__ __align__(16) _Float16 vm[TI * VROW];           // 22848 B

    const int tid = threadIdx.x;
    const int f  = tid & 31;
    const int ch = (tid >> 5) & 1;   // channel half: 0 -> c 0..7, 1 -> c 8..15
    const int jt = tid >> 6;         // column in block 0..7 (wave-uniform)
    const int b  = blockIdx.z;
    const int i0 = blockIdx.y * TI;
    const int jb = blockIdx.x * NCOL;

    // ---- stage x tile: fp32 -> fp16 LDS (23 rows x 10 cols x 2 ch) ----
    if (tid < TROWS * 2 * SCOL) {
        const float* xg = x + (size_t)b * (128 * 128 * 16);
        int r   = tid / (2 * SCOL);
        int k   = tid % (2 * SCOL);
        int cc  = k >> 1;               // 0..9 tile column
        int ch2 = k & 1;
        int col = min(jb + cc, 127);    // clamp: feeds never-stored outputs only
        const float* src = xg + ((size_t)(i0 + r) * 128 + col) * 16 + ch2 * 8;
        float4 lo = *reinterpret_cast<const float4*>(src);
        float4 hi = *reinterpret_cast<const float4*>(src + 4);
        h2 o[4] = { pkrtz(lo.x, lo.y), pkrtz(lo.z, lo.w),
                    pkrtz(hi.x, hi.y), pkrtz(hi.z, hi.w) };
        *reinterpret_cast<float4*>(
            &tile[ch2 * (TROWS * LROW) + r * LROW + cc * 8]) =
            *reinterpret_cast<float4*>(o);
    }

    // ---- stage W packed-h2, TAP-CONTIGUOUS layout ----
    // wl h2-index p*256 + ch*128 + f*4 + q = {W[p, ch*8+2q, f], W[p, ch*8+2q+1, f]}
    {
        h2* wl = reinterpret_cast<h2*>(wbuf);
        auto wstage = [&](int t) {
            int g  = t >> 5;           // p*8 + cpair
            int ff = t & 31;
            int p  = g >> 3;
            int cp = g & 7;            // ch2*4 + q
            int ch2 = cp >> 2;
            int q  = cp & 3;
            wl[p * 256 + ch2 * 128 + ff * 4 + q] =
                pkrtz(Wt[g * 64 + ff], Wt[g * 64 + 32 + ff]);
        };
#pragma unroll
        for (int rr = 0; rr < 4; ++rr) wstage(rr * 512 + tid);
        if (tid < 2304 - 2048) wstage(2048 + tid);
    }

    __syncthreads();   // barrier 1: tile + wbuf read-only from here on

    // ---- read this thread's W frags ONCE via volatile asm (remat-proof,
    // R21-verified resident at VGPR 52). 9x ds_read_b128, conflict-free. ----
    float4 w9[9];
    {
        unsigned wa = (unsigned)(uintptr_t)(&wbuf[0]) + ch * 512 + f * 16;
        asm volatile(
            "ds_read_b128 %0, %9 offset:0\n\t"
            "ds_read_b128 %1, %9 offset:1024\n\t"
            "ds_read_b128 %2, %9 offset:2048\n\t"
            "ds_read_b128 %3, %9 offset:3072\n\t"
            "ds_read_b128 %4, %9 offset:4096\n\t"
            "ds_read_b128 %5, %9 offset:5120\n\t"
            "ds_read_b128 %6, %9 offset:6144\n\t"
            "ds_read_b128 %7, %9 offset:7168\n\t"
            "ds_read_b128 %8, %9 offset:8192\n\t"
            "s_waitcnt lgkmcnt(0)"
            : "=&v"(w9[0]), "=&v"(w9[1]), "=&v"(w9[2]), "=&v"(w9[3]),
              "=&v"(w9[4]), "=&v"(w9[5]), "=&v"(w9[6]), "=&v"(w9[7]),
              "=&v"(w9[8])
            : "v"(wa)
            : "memory");
    }
    const h2* wh0 = reinterpret_cast<const h2*>(&w9[0]);  // taps 0..2 (di=0)
    const h2* wh1 = reinterpret_cast<const h2*>(&w9[3]);  // taps 3..5 (di=1)
    const h2* wh2 = reinterpret_cast<const h2*>(&w9[6]);  // taps 6..8 (di=2)

    const _Float16* lb = &tile[ch * (TROWS * LROW) + jt * 8];  // row 0, col jt

    // prime depth-1 prefetch regs
    float4 pre[3];
#pragma unroll
    for (int dj = 0; dj < 3; ++dj)
        pre[dj] = *reinterpret_cast<const float4*>(lb + dj * 8);

    const _Float16 HINF = (_Float16)__builtin_huge_valf();
    h2 accB = {HINF, HINF};  // partial min for output row r-1
    h2 accC = {HINF, HINF};  // partial min for output row r-2

    // vm slot for this thread: [row][jt][ch][f] with padded col stride
    _Float16* vslot = &vm[jt * VCOL + ch * 32 + f];

    auto body = [&](int r, bool do_prefetch, bool do_vm) {
        h2 n0 = rowmin3(pre, wh0);
        h2 n1 = rowmin3(pre, wh1);
        h2 n2 = rowmin3(pre, wh2);

        if (do_prefetch) {
            const _Float16* ln = lb + (r + 1) * LROW;
#pragma unroll
            for (int dj = 0; dj < 3; ++dj)
                pre[dj] = *reinterpret_cast<const float4*>(ln + dj * 8);
        }

        h2 fin2 = pkmin(accC, n2);  // output row r-2 complete (this ch-half)
        accC = pkmin(accB, n1);
        accB = n0;

        if (do_vm) {
            _Float16 m = minh(fin2[0], fin2[1]);  // v_min_f16
            vslot[(r - 2) * VROW] = m;            // full-wave b16 LDS write
        }
    };

    body(0, true, false);
    body(1, true, false);
#pragma unroll
    for (int r = 2; r < TROWS - 1; ++r)   // FULL unroll: r = 2..21 literal
        body(r, true, true);
    body(TROWS - 1, false, true);         // r = 22, no prefetch

    __syncthreads();   // barrier 2: vm complete

    // ---- merge epilogue: 1344 float4 tasks, 1KB contiguous per wave ----
    {
        float* outb = out + (size_t)b * (126 * 126 * 32);
        auto merge = [&](int t) {
            int row = t >> 6;
            int k   = t & 63;
            int col = k >> 3;
            int q   = k & 7;
            int jj  = jb + col;
            const _Float16* base = &vm[row * VROW + col * VCOL + q * 4];
            h2 a[2], c[2];
            *reinterpret_cast<double*>(a) = *reinterpret_cast<const double*>(base);
            *reinterpret_cast<double*>(c) = *reinterpret_cast<const double*>(base + 32);
            h2 m0 = hmin2(a[0], c[0]);
            h2 m1 = hmin2(a[1], c[1]);
            float4 o = { (float)m0[0], (float)m0[1], (float)m1[0], (float)m1[1] };
            if (jj < 126)
                *reinterpret_cast<float4*>(
                    &outb[((size_t)(i0 + row) * 126 + jj) * 32 + q * 4]) = o;
        };
        merge(tid);
        merge(tid + 512);
        if (tid < TI * 64 - 1024) merge(tid + 1024);  // 320 extra tasks
    }
}

extern "C" void kernel_launch(void* const* d_in, const int* in_sizes, int n_in,
                              void* d_out, int out_size, void* d_ws, size_t ws_size,
                              hipStream_t stream) {
    const float* x  = (const float*)d_in[0];  // 16*128*128*16
    const float* Wt = (const float*)d_in[1];  // 3*3*16*32
    float* out = (float*)d_out;               // 16*126*126*32

    dim3 grid(16, 6, 16);   // 1536 blocks, 8 output cols each
    dim3 block(512);
    erosion_kernel<<<grid, block, 0, stream>>>(x, Wt, out);
}